// Round 8
// baseline (153.025 us; speedup 1.0000x reference)
//
#include <hip/hip_runtime.h>

// Problem constants
#define B_  32
#define M_  64
#define K_  36
#define DS_ 512
#define DX_ 128
#define DQ_ 512
#define H_  256

// kern1 grid: s2 tiles of 8 rows (h-quad mapping), px tiles of 4 rows (old)
#define S2B 512             // 256 tiles x 2 mats
#define PXB 288             // 1152/4 rows
#define QPB 32

// ---------------------------------------------------------------------------
// kern1 (grid 832 x 512): all GEMMs + fused hs.
// s2 blocks use h-quad mapping: lane l owns h=4l..4l+3, wave rg owns rows
// rg*2..rg*2+1, kh = K-half. Per k-quad: 4 float4 W loads (coalesced VMEM)
// + 2 ds_read_b128 A broadcasts feed 32 FMAs -- 4x the FMA-per-mem-instr of
// the round-7 scalar-W form (which capped VALUBusy at ~42%).
//   blocks [0,512):    tile=bid>>1, mat=bid&1.
//     mat=0: pre_s[8 rows] = s2@w_s
//     mat=1: hs[8 rows] = relu(s2@h_w1 + h_b1) @ h_w2   (fused in-block)
//   blocks [512,800):  px[4 rows] = x0@w_x + score_b1   (K=128, round-7 form)
//   blocks [800,832):  qpre[b]    = q[b]@w_q            (K=512, round-7 form)
// ---------------------------------------------------------------------------
__global__ __launch_bounds__(512, 4) void kern1(
    const float* __restrict__ s2,        // (2048,512)
    const float* __restrict__ x0,        // (1152,128)
    const float* __restrict__ q,         // (32,512)
    const float* __restrict__ score_w1,  // (1152,256)
    const float* __restrict__ score_b1,  // (256)
    const float* __restrict__ h_w1,      // (512,256)
    const float* __restrict__ h_b1,      // (256)
    const float* __restrict__ h_w2,      // (256,128)
    float* __restrict__ pre_s,           // (2048,256)
    float* __restrict__ px,              // (1152,256)
    float* __restrict__ qpre,            // (32,256)
    float* __restrict__ hs)              // (2048,128)
{
    __shared__ float As[8 * DS_];        // 16 KB staged A rows
    __shared__ float comb[8 * H_];       // 8 KB split-K combine
    __shared__ float hre[8 * H_];        // 8 KB relu'd h1 rows (mat=1)

    const int t   = threadIdx.x;
    const int bid = blockIdx.x;
    const int l   = t & 63;
    const int kh  = __builtin_amdgcn_readfirstlane(t >> 8);   // wave-uniform

    if (bid < S2B) {                     // ---- s2 GEMMs, h-quad mapping ----
        const int tile = bid >> 1, mat = bid & 1;
        const int rg   = __builtin_amdgcn_readfirstlane((t >> 6) & 3);
        const float* W = mat ? h_w1 : score_w1;               // (512,256)

        {   // stage 8 rows of s2 (16 KB), two float4 per thread, coalesced
            const float* Asrc = s2 + (size_t)tile * 8 * DS_;
            *(float4*)&As[t * 4]        = *(const float4*)(Asrc + t * 4);
            *(float4*)&As[t * 4 + 2048] = *(const float4*)(Asrc + t * 4 + 2048);
        }
        __syncthreads();

        const float4* Wq = (const float4*)(W + (size_t)(kh * 256) * H_) + l;
        const int r0 = rg * 2;           // wave-uniform row pair
        const int ab = kh * 256;         // wave-uniform A k-base

        float4 acc0 = make_float4(0.f, 0.f, 0.f, 0.f);
        float4 acc1 = make_float4(0.f, 0.f, 0.f, 0.f);

        #pragma unroll 2
        for (int k = 0; k < 256; k += 4) {
            const float4 w0  = Wq[(size_t)(k + 0) * 64];
            const float4 w1  = Wq[(size_t)(k + 1) * 64];
            const float4 w2v = Wq[(size_t)(k + 2) * 64];
            const float4 w3  = Wq[(size_t)(k + 3) * 64];
            const float4 a0 = *(const float4*)&As[(r0 + 0) * DS_ + ab + k];
            const float4 a1 = *(const float4*)&As[(r0 + 1) * DS_ + ab + k];
            // acc[j] += sum_i A[row][k+i] * W[k+i][4l+j]
            acc0.x = fmaf(a0.x, w0.x, acc0.x);
            acc0.y = fmaf(a0.x, w0.y, acc0.y);
            acc0.z = fmaf(a0.x, w0.z, acc0.z);
            acc0.w = fmaf(a0.x, w0.w, acc0.w);
            acc0.x = fmaf(a0.y, w1.x, acc0.x);
            acc0.y = fmaf(a0.y, w1.y, acc0.y);
            acc0.z = fmaf(a0.y, w1.z, acc0.z);
            acc0.w = fmaf(a0.y, w1.w, acc0.w);
            acc0.x = fmaf(a0.z, w2v.x, acc0.x);
            acc0.y = fmaf(a0.z, w2v.y, acc0.y);
            acc0.z = fmaf(a0.z, w2v.z, acc0.z);
            acc0.w = fmaf(a0.z, w2v.w, acc0.w);
            acc0.x = fmaf(a0.w, w3.x, acc0.x);
            acc0.y = fmaf(a0.w, w3.y, acc0.y);
            acc0.z = fmaf(a0.w, w3.z, acc0.z);
            acc0.w = fmaf(a0.w, w3.w, acc0.w);
            acc1.x = fmaf(a1.x, w0.x, acc1.x);
            acc1.y = fmaf(a1.x, w0.y, acc1.y);
            acc1.z = fmaf(a1.x, w0.z, acc1.z);
            acc1.w = fmaf(a1.x, w0.w, acc1.w);
            acc1.x = fmaf(a1.y, w1.x, acc1.x);
            acc1.y = fmaf(a1.y, w1.y, acc1.y);
            acc1.z = fmaf(a1.y, w1.z, acc1.z);
            acc1.w = fmaf(a1.y, w1.w, acc1.w);
            acc1.x = fmaf(a1.z, w2v.x, acc1.x);
            acc1.y = fmaf(a1.z, w2v.y, acc1.y);
            acc1.z = fmaf(a1.z, w2v.z, acc1.z);
            acc1.w = fmaf(a1.z, w2v.w, acc1.w);
            acc1.x = fmaf(a1.w, w3.x, acc1.x);
            acc1.y = fmaf(a1.w, w3.y, acc1.y);
            acc1.z = fmaf(a1.w, w3.z, acc1.z);
            acc1.w = fmaf(a1.w, w3.w, acc1.w);
        }

        if (kh) {
            *(float4*)&comb[(r0 + 0) * H_ + l * 4] = acc0;
            *(float4*)&comb[(r0 + 1) * H_ + l * 4] = acc1;
        }
        __syncthreads();
        if (!kh) {
            const float4 c0 = *(const float4*)&comb[(r0 + 0) * H_ + l * 4];
            const float4 c1 = *(const float4*)&comb[(r0 + 1) * H_ + l * 4];
            if (!mat) {
                float4 o0 = make_float4(acc0.x + c0.x, acc0.y + c0.y,
                                        acc0.z + c0.z, acc0.w + c0.w);
                float4 o1 = make_float4(acc1.x + c1.x, acc1.y + c1.y,
                                        acc1.z + c1.z, acc1.w + c1.w);
                float* dst = pre_s + ((size_t)tile * 8 + r0) * H_ + l * 4;
                *(float4*)dst        = o0;
                *(float4*)(dst + H_) = o1;
            } else {
                const float4 bv = *(const float4*)(h_b1 + l * 4);
                float4 o0, o1;
                o0.x = fmaxf(acc0.x + c0.x + bv.x, 0.f);
                o0.y = fmaxf(acc0.y + c0.y + bv.y, 0.f);
                o0.z = fmaxf(acc0.z + c0.z + bv.z, 0.f);
                o0.w = fmaxf(acc0.w + c0.w + bv.w, 0.f);
                o1.x = fmaxf(acc1.x + c1.x + bv.x, 0.f);
                o1.y = fmaxf(acc1.y + c1.y + bv.y, 0.f);
                o1.z = fmaxf(acc1.z + c1.z + bv.z, 0.f);
                o1.w = fmaxf(acc1.w + c1.w + bv.w, 0.f);
                *(float4*)&hre[(r0 + 0) * H_ + l * 4] = o0;
                *(float4*)&hre[(r0 + 1) * H_ + l * 4] = o1;
            }
        }
        if (mat) {                       // fused hs = hre @ h_w2
            __syncthreads();
            const int row = __builtin_amdgcn_readfirstlane(t >> 6); // 0..7
            const int f0  = l * 2;
            const float* w2p = h_w2 + f0;
            float s0 = 0.f, s1 = 0.f;
            #pragma unroll 2
            for (int k = 0; k < H_; k += 4) {
                const float4 hv = *(const float4*)&hre[row * H_ + k];
                const float2 wa = *(const float2*)(w2p + (size_t)(k + 0) * DX_);
                const float2 wb = *(const float2*)(w2p + (size_t)(k + 1) * DX_);
                const float2 wc = *(const float2*)(w2p + (size_t)(k + 2) * DX_);
                const float2 wd = *(const float2*)(w2p + (size_t)(k + 3) * DX_);
                s0 = fmaf(hv.x, wa.x, s0); s1 = fmaf(hv.x, wa.y, s1);
                s0 = fmaf(hv.y, wb.x, s0); s1 = fmaf(hv.y, wb.y, s1);
                s0 = fmaf(hv.z, wc.x, s0); s1 = fmaf(hv.z, wc.y, s1);
                s0 = fmaf(hv.w, wd.x, s0); s1 = fmaf(hv.w, wd.y, s1);
            }
            *(float2*)(hs + ((size_t)tile * 8 + row) * DX_ + f0) =
                make_float2(s0, s1);
        }

    } else if (bid < S2B + PXB) {        // ---- px blocks (K=128) ----
        const int tile = bid - S2B;
        const int h    = t & 255;

        if (t < 128) {                   // stage 4 rows of x0 (2 KB)
            const float* Asrc = x0 + (size_t)tile * 4 * DX_;
            *(float4*)&As[t * 4] = *(const float4*)(Asrc + t * 4);
        }
        __syncthreads();

        const float* Wp = score_w1 + (size_t)(DS_ + kh * 64) * H_ + h;
        const int ab = kh * 64;

        float acc[4];
        #pragma unroll
        for (int r = 0; r < 4; ++r) acc[r] = 0.f;

        #pragma unroll 2
        for (int k = 0; k < 64; k += 4) {
            const float b0 = Wp[(size_t)(k + 0) * H_];
            const float b1 = Wp[(size_t)(k + 1) * H_];
            const float b2 = Wp[(size_t)(k + 2) * H_];
            const float b3 = Wp[(size_t)(k + 3) * H_];
            #pragma unroll
            for (int r = 0; r < 4; ++r) {
                const float4 a = *(const float4*)&As[r * DX_ + ab + k];
                acc[r] = fmaf(a.x, b0, acc[r]);
                acc[r] = fmaf(a.y, b1, acc[r]);
                acc[r] = fmaf(a.z, b2, acc[r]);
                acc[r] = fmaf(a.w, b3, acc[r]);
            }
        }
        if (kh) {
            #pragma unroll
            for (int r = 0; r < 4; ++r) comb[r * H_ + h] = acc[r];
        }
        __syncthreads();
        if (!kh) {
            const float b1v = score_b1[h];
            float* dst = px + (size_t)tile * 4 * H_ + h;
            #pragma unroll
            for (int r = 0; r < 4; ++r)
                dst[(size_t)r * H_] = acc[r] + comb[r * H_ + h] + b1v;
        }

    } else {                             // ---- qpre blocks ----
        const int b = bid - (S2B + PXB);
        const int h = t & 255;

        if (t < 128) {                   // stage q row (2 KB)
            const float* Asrc = q + (size_t)b * DQ_;
            *(float4*)&As[t * 4] = *(const float4*)(Asrc + t * 4);
        }
        __syncthreads();

        const float* wq = score_w1 + (size_t)(DS_ + DX_ + kh * 256) * H_ + h;
        const int qb = kh * 256;
        float a0 = 0.f, a1 = 0.f, a2 = 0.f, a3 = 0.f;
        #pragma unroll 2
        for (int d = 0; d < 256; d += 4) {
            const float4 q4 = *(const float4*)&As[qb + d];
            a0 = fmaf(q4.x, wq[(size_t)(d + 0) * H_], a0);
            a1 = fmaf(q4.y, wq[(size_t)(d + 1) * H_], a1);
            a2 = fmaf(q4.z, wq[(size_t)(d + 2) * H_], a2);
            a3 = fmaf(q4.w, wq[(size_t)(d + 3) * H_], a3);
        }
        const float s = (a0 + a1) + (a2 + a3);
        if (kh) comb[h] = s;
        __syncthreads();
        if (!kh) qpre[(size_t)b * H_ + h] = s + comb[h];
    }
}

// ---------------------------------------------------------------------------
// kern3 (grid 1152 = one block per (b,k), 256 threads): logits+softmax+agg.
// (unchanged -- verified correct rounds 4-7)
// ---------------------------------------------------------------------------
__global__ __launch_bounds__(256) void kern3(
    const float* __restrict__ pre_s,     // (2048,256)
    const float* __restrict__ px,        // (1152,256)
    const float* __restrict__ qpre,      // (32,256)
    const float* __restrict__ score_w2,  // (256,1)
    const float* __restrict__ hs,        // (2048,128)
    const float* __restrict__ h_b2,      // (128)
    const float* __restrict__ x0,        // (1152,128)
    float* __restrict__ out)             // (1152,256)
{
    __shared__ float logit[M_];
    __shared__ float att[M_];
    __shared__ float pr[DX_];

    const int t    = threadIdx.x;
    const int bk   = blockIdx.x;
    const int b    = bk / K_;
    const int lane = t & 63, wave = t >> 6;
    const int hq   = lane << 2;          // h-quad base: 4 h's per lane

    float4 c4, v4;
    {
        const float4 qv = *(const float4*)(qpre + (size_t)b * H_ + hq);
        const float4 pv = *(const float4*)(px + (size_t)bk * H_ + hq);
        c4.x = qv.x + pv.x; c4.y = qv.y + pv.y;
        c4.z = qv.z + pv.z; c4.w = qv.w + pv.w;
        v4 = *(const float4*)(score_w2 + hq);
    }

    const float* ps = pre_s + (size_t)b * M_ * H_;
    #pragma unroll 2
    for (int mi = 0; mi < 16; ++mi) {
        const int m = wave * 16 + mi;
        const float4 p = *(const float4*)(ps + (size_t)m * H_ + hq);
        float x = fmaxf(p.x + c4.x, 0.f) * v4.x
                + fmaxf(p.y + c4.y, 0.f) * v4.y
                + fmaxf(p.z + c4.z, 0.f) * v4.z
                + fmaxf(p.w + c4.w, 0.f) * v4.w;
        #pragma unroll
        for (int off = 32; off > 0; off >>= 1)
            x += __shfl_xor(x, off, 64);
        if (lane == 0) logit[m] = x;
    }
    __syncthreads();

    if (wave == 0) {
        const float L = logit[lane];
        float mx = L;
        #pragma unroll
        for (int off = 32; off > 0; off >>= 1)
            mx = fmaxf(mx, __shfl_xor(mx, off, 64));
        const float e = expf(L - mx);
        float sm = e;
        #pragma unroll
        for (int off = 32; off > 0; off >>= 1)
            sm += __shfl_xor(sm, off, 64);
        att[lane] = e / sm;
    }
    __syncthreads();

    const int f = t & 127, mh = t >> 7;
    {
        const float* hsp = hs + ((size_t)b * M_ + mh * 32) * DX_ + f;
        float r = 0.f;
        #pragma unroll 4
        for (int m2 = 0; m2 < 32; ++m2)
            r = fmaf(att[mh * 32 + m2], hsp[(size_t)m2 * DX_], r);
        if (mh) pr[f] = r;
        __syncthreads();
        if (!mh)
            out[(size_t)bk * (2 * DX_) + DX_ + f] = r + pr[f] + h_b2[f];
    }
    if (t < DX_)
        out[(size_t)bk * (2 * DX_) + t] = x0[(size_t)bk * DX_ + t];
}

extern "C" void kernel_launch(void* const* d_in, const int* in_sizes, int n_in,
                              void* d_out, int out_size, void* d_ws, size_t ws_size,
                              hipStream_t stream) {
    (void)in_sizes; (void)n_in; (void)out_size; (void)ws_size;
    const float* s2       = (const float*)d_in[0];
    const float* x0       = (const float*)d_in[1];
    const float* q        = (const float*)d_in[2];
    const float* score_w1 = (const float*)d_in[3];
    const float* score_b1 = (const float*)d_in[4];
    const float* score_w2 = (const float*)d_in[5];
    // d_in[6] = score_b2 (cancels in softmax)
    const float* h_w1     = (const float*)d_in[7];
    const float* h_b1     = (const float*)d_in[8];
    const float* h_w2     = (const float*)d_in[9];
    const float* h_b2     = (const float*)d_in[10];
    float* out = (float*)d_out;

    float* ws    = (float*)d_ws;
    float* pre_s = ws;                                   // 2048*256
    float* px    = pre_s + (size_t)B_ * M_ * H_;         // 1152*256
    float* qpre  = px    + (size_t)B_ * K_ * H_;         // 32*256
    float* hs    = qpre  + (size_t)B_ * H_;              // 2048*128

    kern1<<<S2B + PXB + QPB, 512, 0, stream>>>(
        s2, x0, q, score_w1, score_b1, h_w1, h_b1, h_w2,
        pre_s, px, qpre, hs);
    kern3<<<B_ * K_, 256, 0, stream>>>(pre_s, px, qpre, score_w2, hs, h_b2,
                                       x0, out);
}

// Round 9
// 134.153 us; speedup vs baseline: 1.1407x; 1.1407x over previous
//
#include <hip/hip_runtime.h>

// Problem constants
#define B_  32
#define M_  64
#define K_  36
#define DS_ 512
#define DX_ 128
#define DQ_ 512
#define H_  256

// kern1 grid: ROWS=4 per tile, in-block split-K=2 (512 threads)
#define S2B 1024            // 512 tiles x 2 mats
#define PXB 288             // 1152/4 rows
#define QPB 32

// ---------------------------------------------------------------------------
// kern1 (grid 1344 x 512): all GEMMs + fused hs. In-block split-K=2
// (waves 0-3 kh=0, waves 4-7 kh=1), LDS combine, single barriers.
// A rows staged in LDS (ds_read_b128 broadcasts). W per-lane scalar global
// loads -- 256 INDEPENDENT loads per thread; unroll 8 exposes 32 at a time
// so the compiler can software-pipeline with counted vmcnt (round-7's
// unroll-2 kept only ~4 in flight -> L2-latency stall per k-quad).
//   blocks [0,1024):    tile=bid>>1, mat=bid&1.
//     mat=0: pre_s[4 rows] = s2@w_s
//     mat=1: hs[4 rows] = relu(s2@h_w1 + h_b1) @ h_w2     (fused, in-block)
//   blocks [1024,1312): px[4 rows] = x0@w_x + score_b1    (K=128)
//   blocks [1312,1344): qpre[b]    = q[b]@w_q             (K=512)
// ---------------------------------------------------------------------------
__global__ __launch_bounds__(512, 6) void kern1(
    const float* __restrict__ s2,        // (2048,512)
    const float* __restrict__ x0,        // (1152,128)
    const float* __restrict__ q,         // (32,512)
    const float* __restrict__ score_w1,  // (1152,256)
    const float* __restrict__ score_b1,  // (256)
    const float* __restrict__ h_w1,      // (512,256)
    const float* __restrict__ h_b1,      // (256)
    const float* __restrict__ h_w2,      // (256,128)
    float* __restrict__ pre_s,           // (2048,256)
    float* __restrict__ px,              // (1152,256)
    float* __restrict__ qpre,            // (32,256)
    float* __restrict__ hs)              // (2048,128)
{
    __shared__ float As[4 * DS_];        // 8 KB staged A rows
    __shared__ float comb[4 * H_];       // 4 KB split-K combine
    __shared__ float hre[4 * H_];        // 4 KB relu'd h1 rows (mat=1)

    const int t   = threadIdx.x;
    const int bid = blockIdx.x;
    const int h   = t & 255;
    const int kh  = __builtin_amdgcn_readfirstlane(t >> 8);   // wave-uniform

    if (bid < S2B) {                     // ---- s2 GEMMs ----
        const int tile = bid >> 1, mat = bid & 1;
        const float* W = mat ? h_w1 : score_w1;               // (512,256)

        // stage 4 rows of s2 (8 KB), one float4 per thread, coalesced
        {
            const float* Asrc = s2 + (size_t)tile * 4 * DS_;
            *(float4*)&As[t * 4] = *(const float4*)(Asrc + t * 4);
        }
        __syncthreads();

        const float* Wp = W + (size_t)(kh * 256) * H_ + h;
        const int ab = kh * 256;         // wave-uniform A base within row

        float acc[4];
        #pragma unroll
        for (int r = 0; r < 4; ++r) acc[r] = 0.f;

        #pragma unroll 8
        for (int k = 0; k < 256; k += 4) {
            const float b0 = Wp[(size_t)(k + 0) * H_];
            const float b1 = Wp[(size_t)(k + 1) * H_];
            const float b2 = Wp[(size_t)(k + 2) * H_];
            const float b3 = Wp[(size_t)(k + 3) * H_];
            #pragma unroll
            for (int r = 0; r < 4; ++r) {
                const float4 a = *(const float4*)&As[r * DS_ + ab + k];
                acc[r] = fmaf(a.x, b0, acc[r]);
                acc[r] = fmaf(a.y, b1, acc[r]);
                acc[r] = fmaf(a.z, b2, acc[r]);
                acc[r] = fmaf(a.w, b3, acc[r]);
            }
        }

        if (kh) {
            #pragma unroll
            for (int r = 0; r < 4; ++r) comb[r * H_ + h] = acc[r];
        }
        __syncthreads();

        if (!mat) {                      // pre_s: plain store
            if (!kh) {
                float* dst = pre_s + (size_t)tile * 4 * H_ + h;
                #pragma unroll
                for (int r = 0; r < 4; ++r)
                    dst[(size_t)r * H_] = acc[r] + comb[r * H_ + h];
            }
        } else {                         // fused hs = relu(h1+b1) @ h_w2
            if (!kh) {
                const float b1v = h_b1[h];
                #pragma unroll
                for (int r = 0; r < 4; ++r)
                    hre[r * H_ + h] =
                        fmaxf(acc[r] + comb[r * H_ + h] + b1v, 0.f);
            }
            __syncthreads();

            const int row = t >> 7;      // 0..3 (wave-uniform)
            const int f   = t & 127;
            const float* w2p = h_w2 + f;
            float o0 = 0.f, o1 = 0.f, o2 = 0.f, o3 = 0.f;
            #pragma unroll 4
            for (int k = 0; k < H_; k += 4) {
                o0 = fmaf(hre[row * H_ + k + 0], w2p[(size_t)(k + 0) * DX_], o0);
                o1 = fmaf(hre[row * H_ + k + 1], w2p[(size_t)(k + 1) * DX_], o1);
                o2 = fmaf(hre[row * H_ + k + 2], w2p[(size_t)(k + 2) * DX_], o2);
                o3 = fmaf(hre[row * H_ + k + 3], w2p[(size_t)(k + 3) * DX_], o3);
            }
            hs[((size_t)tile * 4 + row) * DX_ + f] = (o0 + o1) + (o2 + o3);
        }

    } else if (bid < S2B + PXB) {        // ---- px blocks (K=128) ----
        const int tile = bid - S2B;

        if (t < 128) {                   // stage 4 rows of x0 (2 KB)
            const float* Asrc = x0 + (size_t)tile * 4 * DX_;
            *(float4*)&As[t * 4] = *(const float4*)(Asrc + t * 4);
        }
        __syncthreads();

        const float* Wp = score_w1 + (size_t)(DS_ + kh * 64) * H_ + h;
        const int ab = kh * 64;

        float acc[4];
        #pragma unroll
        for (int r = 0; r < 4; ++r) acc[r] = 0.f;

        #pragma unroll 4
        for (int k = 0; k < 64; k += 4) {
            const float b0 = Wp[(size_t)(k + 0) * H_];
            const float b1 = Wp[(size_t)(k + 1) * H_];
            const float b2 = Wp[(size_t)(k + 2) * H_];
            const float b3 = Wp[(size_t)(k + 3) * H_];
            #pragma unroll
            for (int r = 0; r < 4; ++r) {
                const float4 a = *(const float4*)&As[r * DX_ + ab + k];
                acc[r] = fmaf(a.x, b0, acc[r]);
                acc[r] = fmaf(a.y, b1, acc[r]);
                acc[r] = fmaf(a.z, b2, acc[r]);
                acc[r] = fmaf(a.w, b3, acc[r]);
            }
        }
        if (kh) {
            #pragma unroll
            for (int r = 0; r < 4; ++r) comb[r * H_ + h] = acc[r];
        }
        __syncthreads();
        if (!kh) {
            const float b1v = score_b1[h];
            float* dst = px + (size_t)tile * 4 * H_ + h;
            #pragma unroll
            for (int r = 0; r < 4; ++r)
                dst[(size_t)r * H_] = acc[r] + comb[r * H_ + h] + b1v;
        }

    } else {                             // ---- qpre blocks ----
        const int b = bid - (S2B + PXB);

        if (t < 128) {                   // stage q row (2 KB)
            const float* Asrc = q + (size_t)b * DQ_;
            *(float4*)&As[t * 4] = *(const float4*)(Asrc + t * 4);
        }
        __syncthreads();

        const float* wq = score_w1 + (size_t)(DS_ + DX_ + kh * 256) * H_ + h;
        const int qb = kh * 256;
        float a0 = 0.f, a1 = 0.f, a2 = 0.f, a3 = 0.f;
        #pragma unroll 8
        for (int d = 0; d < 256; d += 4) {
            const float4 q4 = *(const float4*)&As[qb + d];
            a0 = fmaf(q4.x, wq[(size_t)(d + 0) * H_], a0);
            a1 = fmaf(q4.y, wq[(size_t)(d + 1) * H_], a1);
            a2 = fmaf(q4.z, wq[(size_t)(d + 2) * H_], a2);
            a3 = fmaf(q4.w, wq[(size_t)(d + 3) * H_], a3);
        }
        const float s = (a0 + a1) + (a2 + a3);
        if (kh) comb[h] = s;
        __syncthreads();
        if (!kh) qpre[(size_t)b * H_ + h] = s + comb[h];
    }
}

// ---------------------------------------------------------------------------
// kern3 (grid 1152 = one block per (b,k), 256 threads): logits+softmax+agg.
// Lane = h-quad (float4, coalesced); wave handles 16 m's with 6-step
// shfl_xor reduce; softmax in wave 0; agg reads precomputed hs.
// (round-7 form; mi-loop unroll 2 -> 4 for load pipelining)
// ---------------------------------------------------------------------------
__global__ __launch_bounds__(256) void kern3(
    const float* __restrict__ pre_s,     // (2048,256)
    const float* __restrict__ px,        // (1152,256)
    const float* __restrict__ qpre,      // (32,256)
    const float* __restrict__ score_w2,  // (256,1)
    const float* __restrict__ hs,        // (2048,128)
    const float* __restrict__ h_b2,      // (128)
    const float* __restrict__ x0,        // (1152,128)
    float* __restrict__ out)             // (1152,256)
{
    __shared__ float logit[M_];
    __shared__ float att[M_];
    __shared__ float pr[DX_];

    const int t    = threadIdx.x;
    const int bk   = blockIdx.x;
    const int b    = bk / K_;
    const int lane = t & 63, wave = t >> 6;
    const int hq   = lane << 2;          // h-quad base: 4 h's per lane

    float4 c4, v4;
    {
        const float4 qv = *(const float4*)(qpre + (size_t)b * H_ + hq);
        const float4 pv = *(const float4*)(px + (size_t)bk * H_ + hq);
        c4.x = qv.x + pv.x; c4.y = qv.y + pv.y;
        c4.z = qv.z + pv.z; c4.w = qv.w + pv.w;
        v4 = *(const float4*)(score_w2 + hq);
    }

    const float* ps = pre_s + (size_t)b * M_ * H_;
    #pragma unroll 4
    for (int mi = 0; mi < 16; ++mi) {
        const int m = wave * 16 + mi;
        const float4 p = *(const float4*)(ps + (size_t)m * H_ + hq);
        float x = fmaxf(p.x + c4.x, 0.f) * v4.x
                + fmaxf(p.y + c4.y, 0.f) * v4.y
                + fmaxf(p.z + c4.z, 0.f) * v4.z
                + fmaxf(p.w + c4.w, 0.f) * v4.w;
        #pragma unroll
        for (int off = 32; off > 0; off >>= 1)
            x += __shfl_xor(x, off, 64);
        if (lane == 0) logit[m] = x;
    }
    __syncthreads();

    if (wave == 0) {
        const float L = logit[lane];
        float mx = L;
        #pragma unroll
        for (int off = 32; off > 0; off >>= 1)
            mx = fmaxf(mx, __shfl_xor(mx, off, 64));
        const float e = expf(L - mx);
        float sm = e;
        #pragma unroll
        for (int off = 32; off > 0; off >>= 1)
            sm += __shfl_xor(sm, off, 64);
        att[lane] = e / sm;
    }
    __syncthreads();

    const int f = t & 127, mh = t >> 7;
    {
        const float* hsp = hs + ((size_t)b * M_ + mh * 32) * DX_ + f;
        float r = 0.f;
        #pragma unroll 4
        for (int m2 = 0; m2 < 32; ++m2)
            r = fmaf(att[mh * 32 + m2], hsp[(size_t)m2 * DX_], r);
        if (mh) pr[f] = r;
        __syncthreads();
        if (!mh)
            out[(size_t)bk * (2 * DX_) + DX_ + f] = r + pr[f] + h_b2[f];
    }
    if (t < DX_)
        out[(size_t)bk * (2 * DX_) + t] = x0[(size_t)bk * DX_ + t];
}

extern "C" void kernel_launch(void* const* d_in, const int* in_sizes, int n_in,
                              void* d_out, int out_size, void* d_ws, size_t ws_size,
                              hipStream_t stream) {
    (void)in_sizes; (void)n_in; (void)out_size; (void)ws_size;
    const float* s2       = (const float*)d_in[0];
    const float* x0       = (const float*)d_in[1];
    const float* q        = (const float*)d_in[2];
    const float* score_w1 = (const float*)d_in[3];
    const float* score_b1 = (const float*)d_in[4];
    const float* score_w2 = (const float*)d_in[5];
    // d_in[6] = score_b2 (cancels in softmax)
    const float* h_w1     = (const float*)d_in[7];
    const float* h_b1     = (const float*)d_in[8];
    const float* h_w2     = (const float*)d_in[9];
    const float* h_b2     = (const float*)d_in[10];
    float* out = (float*)d_out;

    float* ws    = (float*)d_ws;
    float* pre_s = ws;                                   // 2048*256
    float* px    = pre_s + (size_t)B_ * M_ * H_;         // 1152*256
    float* qpre  = px    + (size_t)B_ * K_ * H_;         // 32*256
    float* hs    = qpre  + (size_t)B_ * H_;              // 2048*128

    kern1<<<S2B + PXB + QPB, 512, 0, stream>>>(
        s2, x0, q, score_w1, score_b1, h_w1, h_b1, h_w2,
        pre_s, px, qpre, hs);
    kern3<<<B_ * K_, 256, 0, stream>>>(pre_s, px, qpre, score_w2, hs, h_b2,
                                       x0, out);
}